// Round 1
// baseline (603.047 us; speedup 1.0000x reference)
//
#include <hip/hip_runtime.h>

// GAE encoder: 2-layer GCN on MI355X.
// Pipeline: hist -> scan(3) -> dinv -> fill CSR -> [gemm+scale -> aggregate] x2

// ---------------- CSR build ----------------

__global__ __launch_bounds__(256) void hist_kernel(const int* __restrict__ col,
                                                   int* __restrict__ counts, int E) {
    int i = blockIdx.x * 256 + threadIdx.x;
    if (i < E) atomicAdd(&counts[col[i]], 1);
}

// exclusive scan, phase A: per-block (1024 elems) Hillis-Steele
__global__ __launch_bounds__(1024) void scan_a(const int* __restrict__ counts,
                                               int* __restrict__ rp,
                                               int* __restrict__ bsums, int n) {
    __shared__ int s[2][1024];
    int t = threadIdx.x;
    int i = blockIdx.x * 1024 + t;
    int v = (i < n) ? counts[i] : 0;
    s[0][t] = v;
    __syncthreads();
    int p = 0;
    for (int d = 1; d < 1024; d <<= 1) {
        int val = s[p][t] + ((t >= d) ? s[p][t - d] : 0);
        s[p ^ 1][t] = val;
        p ^= 1;
        __syncthreads();
    }
    if (i < n) rp[i] = s[p][t] - v;            // exclusive within block
    if (t == 1023) bsums[blockIdx.x] = s[p][t]; // block total
}

// phase B: scan the (<=128) block sums in one block
__global__ __launch_bounds__(128) void scan_b(int* __restrict__ bsums, int nb) {
    __shared__ int s[2][128];
    int t = threadIdx.x;
    int v = (t < nb) ? bsums[t] : 0;
    s[0][t] = v;
    __syncthreads();
    int p = 0;
    for (int d = 1; d < 128; d <<= 1) {
        int val = s[p][t] + ((t >= d) ? s[p][t - d] : 0);
        s[p ^ 1][t] = val;
        p ^= 1;
        __syncthreads();
    }
    if (t < nb) bsums[t] = s[p][t] - v;         // exclusive
}

// phase C: add block offsets; write rp[n] = E
__global__ __launch_bounds__(256) void scan_c(int* __restrict__ rp,
                                              const int* __restrict__ bsums, int n, int E) {
    int i = blockIdx.x * 256 + threadIdx.x;
    if (i < n)       rp[i] += bsums[i >> 10];
    else if (i == n) rp[n] = E;
}

__global__ __launch_bounds__(256) void dinv_kernel(const int* __restrict__ counts,
                                                   float* __restrict__ dinv, int n) {
    int i = blockIdx.x * 256 + threadIdx.x;
    if (i < n) dinv[i] = rsqrtf((float)(counts[i] + 1)); // +1 = self loop
}

__global__ __launch_bounds__(256) void fill_kernel(const int* __restrict__ row,
                                                   const int* __restrict__ col,
                                                   const int* __restrict__ rp,
                                                   int* __restrict__ fill,
                                                   int* __restrict__ csr, int E) {
    int i = blockIdx.x * 256 + threadIdx.x;
    if (i < E) {
        int c = col[i];
        int p = rp[c] + atomicAdd(&fill[c], 1);
        csr[p] = row[i];
    }
}

// ---------------- GEMM: out[m][n] = dinv[m] * sum_k X[m][k] * W[k][n] ----------------
// M x 128 x NCOLS, f32 (no fp32 MFMA on CDNA4 -> vector FMA).
// 64-row x-tile in LDS (pad 132 floats -> 16B-aligned b128 reads, ~2-way bank alias max).
// W (<=64KB) streamed through L1/L2. Micro-tile: 4 rows x (NCOLS/16) cols per thread.

template <int NCOLS>
__global__ __launch_bounds__(256) void gemm_scale(const float* __restrict__ X,
                                                  const float* __restrict__ W,
                                                  const float* __restrict__ dinv,
                                                  float* __restrict__ out, int M) {
    constexpr int K = 128, BM = 64, PAD = 132, CPT = NCOLS / 16;
    __shared__ float xlds[BM * PAD];

    int tid = threadIdx.x;
    int block_row = blockIdx.x * BM;

    // stage x tile (row-major, padded)
    {
        int r  = tid >> 5;   // 0..7
        int k4 = tid & 31;   // 0..31
#pragma unroll
        for (int p = 0; p < 8; ++p) {
            int rr = r + p * 8;
            int gr = block_row + rr;
            if (gr > M - 1) gr = M - 1;
            float4 v = *(const float4*)(X + (size_t)gr * K + k4 * 4);
            *(float4*)(xlds + rr * PAD + k4 * 4) = v;
        }
    }
    __syncthreads();

    int tc = tid & 15;   // col group
    int tr = tid >> 4;   // row group (0..15), 4 rows each

    float acc[4][CPT];
#pragma unroll
    for (int i = 0; i < 4; ++i)
#pragma unroll
        for (int j = 0; j < CPT; ++j) acc[i][j] = 0.0f;

#pragma unroll 4
    for (int k4 = 0; k4 < K / 4; ++k4) {
        float4 xa[4];
#pragma unroll
        for (int i = 0; i < 4; ++i)
            xa[i] = *(const float4*)(xlds + (tr * 4 + i) * PAD + k4 * 4);
#pragma unroll
        for (int kk = 0; kk < 4; ++kk) {
            float wv[CPT];
#pragma unroll
            for (int m = 0; m < CPT / 4; ++m) {
                float4 w4 = *(const float4*)(W + (size_t)(k4 * 4 + kk) * NCOLS + tc * CPT + m * 4);
                wv[m * 4 + 0] = w4.x; wv[m * 4 + 1] = w4.y;
                wv[m * 4 + 2] = w4.z; wv[m * 4 + 3] = w4.w;
            }
#pragma unroll
            for (int i = 0; i < 4; ++i) {
                float xv = (&xa[i].x)[kk];
#pragma unroll
                for (int j = 0; j < CPT; ++j) acc[i][j] = fmaf(xv, wv[j], acc[i][j]);
            }
        }
    }

#pragma unroll
    for (int i = 0; i < 4; ++i) {
        int r = block_row + tr * 4 + i;
        if (r < M) {
            float di = dinv[r];
#pragma unroll
            for (int m = 0; m < CPT / 4; ++m) {
                float4 o;
                o.x = acc[i][m * 4 + 0] * di;
                o.y = acc[i][m * 4 + 1] * di;
                o.z = acc[i][m * 4 + 2] * di;
                o.w = acc[i][m * 4 + 3] * di;
                *(float4*)(out + (size_t)r * NCOLS + tc * CPT + m * 4) = o;
            }
        }
    }
}

// ---------------- Aggregation: one wave per node ----------------
// h[c] = relu(dinv[c] * (xws[c] + sum_{r->c} xws[r]) + b)

__global__ __launch_bounds__(256) void agg128(const float* __restrict__ xws,
                                              const int* __restrict__ rp,
                                              const int* __restrict__ csr,
                                              const float* __restrict__ dinv,
                                              const float* __restrict__ bias,
                                              float* __restrict__ h, int n) {
    int gid  = blockIdx.x * 256 + threadIdx.x;
    int node = gid >> 6;
    int lane = gid & 63;
    if (node >= n) return;

    const float2* base = (const float2*)xws;
    float2 acc = base[(size_t)node * 64 + lane];   // self-loop term
    int beg = rp[node], end = rp[node + 1];
    int s_next = (beg < end) ? csr[beg] : 0;
    for (int e = beg; e < end; ++e) {
        int s = s_next;
        if (e + 1 < end) s_next = csr[e + 1];      // prefetch next src id
        float2 v = base[(size_t)s * 64 + lane];
        acc.x += v.x;
        acc.y += v.y;
    }
    float  di = dinv[node];
    float2 b  = ((const float2*)bias)[lane];
    float2 o;
    o.x = fmaxf(fmaf(di, acc.x, b.x), 0.0f);
    o.y = fmaxf(fmaf(di, acc.y, b.y), 0.0f);
    ((float2*)h)[(size_t)node * 64 + lane] = o;
}

__global__ __launch_bounds__(256) void agg64(const float* __restrict__ xws,
                                             const int* __restrict__ rp,
                                             const int* __restrict__ csr,
                                             const float* __restrict__ dinv,
                                             const float* __restrict__ bias,
                                             float* __restrict__ out, int n) {
    int gid  = blockIdx.x * 256 + threadIdx.x;
    int node = gid >> 6;
    int lane = gid & 63;
    if (node >= n) return;

    float acc = xws[(size_t)node * 64 + lane];     // self-loop term
    int beg = rp[node], end = rp[node + 1];
    int s_next = (beg < end) ? csr[beg] : 0;
    for (int e = beg; e < end; ++e) {
        int s = s_next;
        if (e + 1 < end) s_next = csr[e + 1];
        acc += xws[(size_t)s * 64 + lane];
    }
    float di = dinv[node];
    out[(size_t)node * 64 + lane] = fmaf(di, acc, bias[lane]);
}

// ---------------- launch ----------------

static inline size_t align512(size_t x) { return (x + 511) & ~(size_t)511; }

extern "C" void kernel_launch(void* const* d_in, const int* in_sizes, int n_in,
                              void* d_out, int out_size, void* d_ws, size_t ws_size,
                              hipStream_t stream) {
    const float* x   = (const float*)d_in[0];
    const int*   ei  = (const int*)d_in[1];
    const float* W1  = (const float*)d_in[2];
    const float* b1  = (const float*)d_in[3];
    const float* W2  = (const float*)d_in[4];
    const float* b2  = (const float*)d_in[5];
    float*       out = (float*)d_out;

    const int N = in_sizes[0] / 128;   // 100000
    const int E = in_sizes[1] / 2;     // 1600000
    const int* row = ei;
    const int* col = ei + E;

    // workspace carve-up
    char* w = (char*)d_ws;
    size_t off = 0;
    auto take = [&](size_t bytes) { void* p = w + off; off = align512(off + bytes); return p; };
    int*   counts = (int*)  take((size_t)N * 4);
    int*   fill   = (int*)  take((size_t)N * 4);
    size_t zero_bytes = off;                     // counts + fill must start at 0
    int*   rp     = (int*)  take((size_t)(N + 1) * 4);
    int*   bsums  = (int*)  take(512);
    float* dinv   = (float*)take((size_t)N * 4);
    int*   csr    = (int*)  take((size_t)E * 4);
    float* xws    = (float*)take((size_t)N * 128 * 4);  // layer1 xws; reused as layer2 xws
    float* h      = (float*)take((size_t)N * 128 * 4);
    (void)ws_size;

    hipMemsetAsync(d_ws, 0, zero_bytes, stream);

    const int nb = (N + 1023) / 1024;

    hist_kernel<<<(E + 255) / 256, 256, 0, stream>>>(col, counts, E);
    scan_a<<<nb, 1024, 0, stream>>>(counts, rp, bsums, N);
    scan_b<<<1, 128, 0, stream>>>(bsums, nb);
    scan_c<<<(N + 256) / 256, 256, 0, stream>>>(rp, bsums, N, E);
    dinv_kernel<<<(N + 255) / 256, 256, 0, stream>>>(counts, dinv, N);
    fill_kernel<<<(E + 255) / 256, 256, 0, stream>>>(row, col, rp, fill, csr, E);

    // layer 1: xws = dinv * (x @ W1); h = relu(dinv * (self + gathered) + b1)
    gemm_scale<128><<<(N + 63) / 64, 256, 0, stream>>>(x, W1, dinv, xws, N);
    agg128<<<(N + 3) / 4, 256, 0, stream>>>(xws, rp, csr, dinv, b1, h, N);

    // layer 2: xws2 = dinv * (h @ W2); out = dinv * (self + gathered) + b2
    gemm_scale<64><<<(N + 63) / 64, 256, 0, stream>>>(h, W2, dinv, xws, N);
    agg64<<<(N + 3) / 4, 256, 0, stream>>>(xws, rp, csr, dinv, b2, out, N);
}